// Round 7
// baseline (258.155 us; speedup 1.0000x reference)
//
#include <hip/hip_runtime.h>
#include <hip/hip_fp16.h>
#include <stdint.h>

#define M_DIM 64
#define K_DIM 8192
#define N_DIM 28672
#define QGROUP 128
#define PF 4  // B prefetch ring depth (power of 2)

typedef __attribute__((ext_vector_type(4))) float floatx4;
typedef __attribute__((ext_vector_type(8))) _Float16 halfx8;
typedef __attribute__((ext_vector_type(4))) uint32_t uintx4;

// bit_cast via memcpy (works for non-trivially-copyable HIP types)
template <typename T, typename F>
__device__ __forceinline__ T bc(F f) {
  static_assert(sizeof(T) == sizeof(F), "size mismatch");
  T t;
  __builtin_memcpy(&t, &f, sizeof(T));
  return t;
}

// p = two fp16 lanes holding (1024+nib); returns two fp16 of (nib-8)*s
// (1024+nib and 1032 are fp16-exact, same binade -> sub exact; mul RNE =
// exactly the reference's fp16 multiply)  [validated round 6: absmax 0.125]
__device__ __forceinline__ uint32_t dq_pair(uint32_t p, uint32_t s2bits) {
  __half2 v = bc<__half2>(p);
  __half2 z = bc<__half2>(0x64086408u);  // (1032, 1032)
  __half2 s = bc<__half2>(s2bits);
  return bc<uint32_t>(__hmul2(__hsub2(v, z), s));
}

// one packed dword (8 nibbles, consecutive k) -> B fragment (8 fp16) for one n
__device__ __forceinline__ halfx8 dequant8(uint32_t q, uint32_t s2bits) {
  const uint32_t MG = 0x64006400u;  // fp16(1024) in both halves
  uint32_t p01 = ((q & 0x0000000Fu) | ((q << 12) & 0x000F0000u)) | MG;
  uint32_t p23 = (((q >> 8) & 0x0000000Fu) | ((q << 4) & 0x000F0000u)) | MG;
  uint32_t p45 = (((q >> 16) & 0x0000000Fu) | ((q >> 4) & 0x000F0000u)) | MG;
  uint32_t p67 = (((q >> 24) & 0x0000000Fu) | ((q >> 12) & 0x000F0000u)) | MG;
  uintx4 r;
  r.x = dq_pair(p01, s2bits);
  r.y = dq_pair(p23, s2bits);
  r.z = dq_pair(p45, s2bits);
  r.w = dq_pair(p67, s2bits);
  return bc<halfx8>(r);
}

// A fp32 -> fp16 (exact; values are fp16-exact), once, into workspace.
__global__ __launch_bounds__(256) void conv_a(const float* __restrict__ A,
                                              _Float16* __restrict__ Ah) {
  const int i = ((int)blockIdx.x * 256 + (int)threadIdx.x) * 8;
  floatx4 a0 = *(const floatx4*)(A + i);
  floatx4 a1 = *(const floatx4*)(A + i + 4);
  halfx8 h;
#pragma unroll
  for (int j = 0; j < 4; ++j) h[j] = (_Float16)a0[j];
#pragma unroll
  for (int j = 0; j < 4; ++j) h[4 + j] = (_Float16)a1[j];
  *(halfx8*)(Ah + i) = h;
}

// Barrier-free GEMM. Block: 256 threads = 4 independent waves; block tile
// 64m x 256n (wave tile 64m x 64n). No LDS. A fragments per-lane from the
// fp16 copy (L1/L2-hot, 1 MB total). B dequanted in registers from qweight
// with a PF-deep prefetch ring. Split-K over blockIdx.y.
template <int KSLICE, bool SPLIT>
__global__ __launch_bounds__(256, 4) void wq_mfma(
    const _Float16* __restrict__ Ah,    // fp16, M x K (in workspace)
    const int* __restrict__ qweight,    // int32, K/8 x N
    const float* __restrict__ scales,   // fp32, K/128 x N (fp16-exact)
    const float* __restrict__ bias,     // fp32, N (fp16-exact)
    float* __restrict__ part,           // KSPLIT x M x N (fp32)
    float* __restrict__ out) {          // fp32, M x N
  constexpr int STEPS = KSLICE / 32;    // 32 k per step
  constexpr int GROUPS = KSLICE / QGROUP;
  static_assert(STEPS >= PF, "need STEPS >= PF");

  const int tid = (int)threadIdx.x;
  const int w = tid >> 6;
  const int l = tid & 63;
  const int l15 = l & 15;
  const int l4 = l >> 4;
  const int nb = (int)blockIdx.x * 256 + w * 64;
  const int kb = (int)blockIdx.y * KSLICE;
  const int ncol = nb + 4 * l15;  // lane's first n (4 consecutive)

  // A: lane l, frag mf -> rows (l15 + 16*mf), k-chunk l4 (8 halves = 16B)
  const _Float16* abase = Ah + (size_t)l15 * K_DIM + (size_t)(kb + l4 * 8);
  // B: lane l -> packed-k row (kb/8 + 4*t + l4), 4 consecutive n (16B)
  const int* qld = qweight + (size_t)((kb >> 3) + l4) * N_DIM + ncol;
  const float* sptr = scales + (size_t)(kb / QGROUP) * N_DIM + ncol;

  floatx4 acc[4][4];
#pragma unroll
  for (int i = 0; i < 4; ++i)
#pragma unroll
    for (int j = 0; j < 4; ++j) acc[i][j] = (floatx4)(0.0f);

  // B ring prologue: steps 0..PF-1 in flight
  uintx4 qr[PF];
#pragma unroll
  for (int s = 0; s < PF; ++s) {
    qr[s] = *(const uintx4*)qld;
    qld += 4 * (size_t)N_DIM;
  }
  floatx4 scv = *(const floatx4*)sptr;  // group 0 scales
  sptr += N_DIM;

  for (int g = 0; g < GROUPS; ++g) {
    uint32_t s2b[4];
#pragma unroll
    for (int d = 0; d < 4; ++d) {
      unsigned short sb = bc<unsigned short>((_Float16)scv[d]);  // exact
      s2b[d] = (uint32_t)sb * 0x10001u;                          // fp16x2 splat
    }
    floatx4 scn = scv;
    if (g + 1 < GROUPS) scn = *(const floatx4*)sptr;  // next group prefetch
    sptr += N_DIM;
#pragma unroll
    for (int tt = 0; tt < 4; ++tt) {
      const int t = g * 4 + tt;
      // consume ring slot, then refill it for step t+PF
      uintx4 qc = qr[t & (PF - 1)];
      if (t + PF < STEPS) qr[t & (PF - 1)] = *(const uintx4*)qld;
      qld += 4 * (size_t)N_DIM;

      const _Float16* ap = abase + (size_t)t * 32;
      halfx8 afr[4], bfr[4];
#pragma unroll
      for (int mf = 0; mf < 4; ++mf)
        afr[mf] = *(const halfx8*)(ap + (size_t)mf * 16 * K_DIM);
      bfr[0] = dequant8(qc.x, s2b[0]);
      bfr[1] = dequant8(qc.y, s2b[1]);
      bfr[2] = dequant8(qc.z, s2b[2]);
      bfr[3] = dequant8(qc.w, s2b[3]);
#pragma unroll
      for (int mf = 0; mf < 4; ++mf)
#pragma unroll
        for (int d = 0; d < 4; ++d)
          acc[mf][d] = __builtin_amdgcn_mfma_f32_16x16x32_f16(afr[mf], bfr[d],
                                                              acc[mf][d], 0, 0, 0);
    }
    scv = scn;
  }

  // Epilogue. C layout: row = 4*(l>>4) + reg (+16*mf), col = l&15; fragment
  // d's col c is global n = nb + 4*c + d -> 4 fragments at fixed (mf, r) are
  // 4 consecutive n. Output fp32.
  if (SPLIT) {
    float* pbase = part + (size_t)blockIdx.y * ((size_t)M_DIM * N_DIM);
#pragma unroll
    for (int mf = 0; mf < 4; ++mf) {
#pragma unroll
      for (int r = 0; r < 4; ++r) {
        const int m = mf * 16 + l4 * 4 + r;
        floatx4 v = {acc[mf][0][r], acc[mf][1][r], acc[mf][2][r], acc[mf][3][r]};
        *(floatx4*)(pbase + (size_t)m * N_DIM + ncol) = v;
      }
    }
  } else {
    floatx4 bb = *(const floatx4*)(bias + ncol);
#pragma unroll
    for (int mf = 0; mf < 4; ++mf) {
#pragma unroll
      for (int r = 0; r < 4; ++r) {
        const int m = mf * 16 + l4 * 4 + r;
        floatx4 v = {acc[mf][0][r] + bb.x, acc[mf][1][r] + bb.y,
                     acc[mf][2][r] + bb.z, acc[mf][3][r] + bb.w};
        *(floatx4*)(out + (size_t)m * N_DIM + ncol) = v;
      }
    }
  }
}

// Sum KSPLIT fp32 partials + bias -> fp32 out. Division-free grid (28, 64).
template <int KSPLIT>
__global__ __launch_bounds__(256) void wq_reduce(const float* __restrict__ part,
                                                 const float* __restrict__ bias,
                                                 float* __restrict__ out) {
  const int m = (int)blockIdx.y;
  const int n = (int)blockIdx.x * 1024 + (int)threadIdx.x * 4;
  const float* p = part + (size_t)m * N_DIM + n;
  floatx4 s = *(const floatx4*)(bias + n);
#pragma unroll
  for (int q = 0; q < KSPLIT; ++q)
    s += *(const floatx4*)(p + (size_t)q * M_DIM * N_DIM);
  *(floatx4*)(out + (size_t)m * N_DIM + n) = s;
}

extern "C" void kernel_launch(void* const* d_in, const int* in_sizes, int n_in,
                              void* d_out, int out_size, void* d_ws, size_t ws_size,
                              hipStream_t stream) {
  const float* A = (const float*)d_in[0];    // fp32 (64x8192), fp16-exact
  const int* qw = (const int*)d_in[1];       // int32 (1024x28672)
  const float* sc = (const float*)d_in[2];   // fp32 (64x28672), fp16-exact
  const float* bi = (const float*)d_in[3];   // fp32 (28672), fp16-exact
  float* out = (float*)d_out;                // fp32 (64x28672)

  const size_t ah_bytes = (size_t)M_DIM * K_DIM * sizeof(_Float16);  // 1 MB
  _Float16* Ah = (_Float16*)d_ws;
  float* part = (float*)((char*)d_ws + ah_bytes);
  const size_t slice_bytes = (size_t)M_DIM * N_DIM * sizeof(float);  // 7.34 MB

  conv_a<<<(M_DIM * K_DIM / 8) / 256, 256, 0, stream>>>(A, Ah);

  if (ws_size >= ah_bytes + 8 * slice_bytes) {
    dim3 grid(N_DIM / 256, 8);
    wq_mfma<K_DIM / 8, true><<<grid, 256, 0, stream>>>(Ah, qw, sc, bi, part, out);
    wq_reduce<8><<<dim3(N_DIM / 1024, M_DIM), 256, 0, stream>>>(part, bi, out);
  } else if (ws_size >= ah_bytes + 4 * slice_bytes) {
    dim3 grid(N_DIM / 256, 4);
    wq_mfma<K_DIM / 4, true><<<grid, 256, 0, stream>>>(Ah, qw, sc, bi, part, out);
    wq_reduce<4><<<dim3(N_DIM / 1024, M_DIM), 256, 0, stream>>>(part, bi, out);
  } else {
    dim3 grid(N_DIM / 256, 1);
    wq_mfma<K_DIM, false><<<grid, 256, 0, stream>>>(Ah, qw, sc, bi, part, out);
  }
}